// Round 1
// baseline (1298.913 us; speedup 1.0000x reference)
//
#include <hip/hip_runtime.h>
#include <math.h>

typedef __attribute__((ext_vector_type(8))) short short8;
typedef __attribute__((ext_vector_type(4))) float floatx4;
typedef __attribute__((ext_vector_type(4))) float fvec4;

__device__ __forceinline__ float bf2f(unsigned short u) {
    union { unsigned int i; float f; } v;
    v.i = ((unsigned int)u) << 16;
    return v.f;
}
__device__ __forceinline__ unsigned short f2bf(float f) {
    union { float f; unsigned int i; } v;
    v.f = f;
    return (unsigned short)((v.i + 0x7FFFu + ((v.i >> 16) & 1u)) >> 16);
}

// ---------------- fp32 -> bf16 convert ----------------
__global__ __launch_bounds__(256) void cvt_kernel(const float* __restrict__ s,
                                                  unsigned short* __restrict__ d, int n) {
    int i = blockIdx.x * 256 + threadIdx.x;
    if (i < n) d[i] = f2bf(s[i]);
}

// ---------------- LayerNorm over C=192, one wave per row ----------------
// mode 0: src = x (B,3136,192); output row o is shifted-window order
// mode 1: src = xres; dst row o direct
__global__ __launch_bounds__(256) void ln_kernel(const float* __restrict__ src,
                                                 const float* __restrict__ gw,
                                                 const float* __restrict__ bw,
                                                 unsigned short* __restrict__ dst,
                                                 int mode) {
    int o = blockIdx.x * 4 + (threadIdx.x >> 6);
    int lane = threadIdx.x & 63;
    size_t srow;
    if (mode == 0) {
        int win = o / 49, n = o % 49;
        int b = win >> 6, wl = win & 63;
        int wh = wl >> 3, ww = wl & 7;
        int i = n / 7, j = n % 7;
        int pr = (wh * 7 + i + 3) % 56;   // roll(-3): shifted (r) reads source (r+3)%56
        int pc = (ww * 7 + j + 3) % 56;
        srow = ((size_t)b * 3136 + (size_t)(pr * 56 + pc)) * 192;
    } else {
        srow = (size_t)o * 192;
    }
    float v0 = src[srow + lane];
    float v1 = src[srow + lane + 64];
    float v2 = src[srow + lane + 128];
    float s = v0 + v1 + v2;
    float s2 = v0 * v0 + v1 * v1 + v2 * v2;
    #pragma unroll
    for (int off = 32; off > 0; off >>= 1) {
        s += __shfl_xor(s, off);
        s2 += __shfl_xor(s2, off);
    }
    float mean = s * (1.0f / 192.0f);
    float var = s2 * (1.0f / 192.0f) - mean * mean;   // biased var, matches jnp.var
    float inv = rsqrtf(var + 1e-5f);
    size_t drow = (size_t)o * 192;
    dst[drow + lane]       = f2bf((v0 - mean) * inv * gw[lane]       + bw[lane]);
    dst[drow + lane + 64]  = f2bf((v1 - mean) * inv * gw[lane + 64]  + bw[lane + 64]);
    dst[drow + lane + 128] = f2bf((v2 - mean) * inv * gw[lane + 128] + bw[lane + 128]);
}

// ---------------- GEMM: C[m][n] = sum_k A[m][k] * W[n][k] (+bias, epilogue) ----------
// A: M x K bf16 row-major;  W: N x K bf16 row-major.  Tile 128x64, BK=32, 4 waves.
// EPI 0: out bf16 = v+bias               (QKV)
// EPI 1: out bf16 = gelu(v+bias)         (FC1)
// EPI 2: window-reverse + residual x -> outf (PROJ; ldo ignored, C=192)
// EPI 3: outf[(mbase+m)*ldo+n] = resid[...] + v + bias  (FC2)
#define LST 40  // LDS row stride in shorts (80B, 16B-aligned, 2-way bank alias = free)
template <int EPI>
__global__ __launch_bounds__(256) void gemm_nt(const unsigned short* __restrict__ A,
                                               const unsigned short* __restrict__ W,
                                               const float* __restrict__ bias,
                                               int K, int ldo, int mbase,
                                               unsigned short* __restrict__ outb,
                                               float* __restrict__ outf,
                                               const float* __restrict__ resid) {
    __shared__ unsigned short Al[128][LST];
    __shared__ unsigned short Wl[64][LST];
    int tid = threadIdx.x;
    int lane = tid & 63;
    int wv = tid >> 6;
    int wm = wv >> 1, wn = wv & 1;
    int m0 = blockIdx.y * 128;
    int n0 = blockIdx.x * 64;
    int row = tid >> 2, cg = (tid & 3) * 8;
    int quad = lane >> 4, l15 = lane & 15;

    floatx4 acc[4][2];
    floatx4 zero = {0.f, 0.f, 0.f, 0.f};
    #pragma unroll
    for (int a = 0; a < 4; ++a)
        #pragma unroll
        for (int b = 0; b < 2; ++b) acc[a][b] = zero;

    for (int kt = 0; kt < K; kt += 32) {
        __syncthreads();
        *(uint4*)&Al[row][cg]      = *(const uint4*)&A[(size_t)(m0 + row) * K + kt + cg];
        *(uint4*)&Al[row + 64][cg] = *(const uint4*)&A[(size_t)(m0 + row + 64) * K + kt + cg];
        *(uint4*)&Wl[row][cg]      = *(const uint4*)&W[(size_t)(n0 + row) * K + kt + cg];
        __syncthreads();
        short8 af[4], wf[2];
        #pragma unroll
        for (int mt = 0; mt < 4; ++mt)
            af[mt] = *(const short8*)&Al[wm * 64 + mt * 16 + l15][quad * 8];
        #pragma unroll
        for (int nt = 0; nt < 2; ++nt)
            wf[nt] = *(const short8*)&Wl[wn * 32 + nt * 16 + l15][quad * 8];
        #pragma unroll
        for (int mt = 0; mt < 4; ++mt)
            #pragma unroll
            for (int nt = 0; nt < 2; ++nt)
                acc[mt][nt] = __builtin_amdgcn_mfma_f32_16x16x32_bf16(af[mt], wf[nt], acc[mt][nt], 0, 0, 0);
    }

    #pragma unroll
    for (int mt = 0; mt < 4; ++mt) {
        #pragma unroll
        for (int nt = 0; nt < 2; ++nt) {
            #pragma unroll
            for (int r = 0; r < 4; ++r) {
                int m = m0 + wm * 64 + mt * 16 + quad * 4 + r;  // D: row=(lane>>4)*4+reg
                int n = n0 + wn * 32 + nt * 16 + l15;           //    col=lane&15
                float v = acc[mt][nt][r] + bias[n];
                if (EPI == 0) {
                    outb[(size_t)m * ldo + n] = f2bf(v);
                } else if (EPI == 1) {
                    float g = 0.5f * v * (1.0f + erff(v * 0.70710678118654752f));
                    outb[(size_t)m * ldo + n] = f2bf(g);
                } else if (EPI == 2) {
                    int win = m / 49, np = m % 49;
                    int b = win >> 6, wl = win & 63;
                    int wh = wl >> 3, ww = wl & 7;
                    int i = np / 7, j = np % 7;
                    int pr = (wh * 7 + i + 3) % 56;  // window-reverse + roll(+3)
                    int pc = (ww * 7 + j + 3) % 56;
                    size_t dst = ((size_t)b * 3136 + (size_t)(pr * 56 + pc)) * 192 + n;
                    outf[dst] = resid[dst] + v;
                } else {
                    size_t dst = (size_t)(mbase + m) * ldo + n;
                    outf[dst] = resid[dst] + v;
                }
            }
        }
    }
}

// ---------------- windowed attention: one wave per (window, head) ----------------
// qkv rows (w*49+n) x 576: [q 0..191 | k 192..383 | v 384..575], head-major inside.
// 3 heads per block (192 threads) so fp32 K/V LDS stays < 64KB.
__global__ __launch_bounds__(192) void attn_kernel(const unsigned short* __restrict__ qkv,
                                                   const float* __restrict__ btab,
                                                   unsigned short* __restrict__ awin) {
    __shared__ float Kl[3][49][32];
    __shared__ float Vl[3][49][32];
    __shared__ float bl[1014];  // 169 x 6 rel-pos bias table
    int w = blockIdx.x >> 1;
    int hb = (blockIdx.x & 1) * 3;
    int tid = threadIdx.x;
    int hl = tid >> 6;
    int lane = tid & 63;
    int h = hb + hl;
    for (int idx = tid; idx < 1014; idx += 192) bl[idx] = btab[idx];
    const unsigned short* base = qkv + (size_t)w * 49 * 576;
    for (int idx = lane; idx < 1568; idx += 64) {
        int rr = idx >> 5, d = idx & 31;
        Kl[hl][rr][d] = bf2f(base[rr * 576 + 192 + h * 32 + d]);
        Vl[hl][rr][d] = bf2f(base[rr * 576 + 384 + h * 32 + d]);
    }
    float q[32];
    int r = lane;
    if (r < 49) {
        const short8* qp = (const short8*)(base + r * 576 + h * 32);
        #pragma unroll
        for (int t = 0; t < 4; ++t) {
            short8 qv = qp[t];
            #pragma unroll
            for (int e = 0; e < 8; ++e) q[t * 8 + e] = bf2f((unsigned short)qv[e]);
        }
    }
    __syncthreads();
    if (r >= 49) return;  // no further barriers below

    int wl = w & 63, wh = wl >> 3, ww = wl & 7;
    int i1 = r / 7, j1 = r % 7;
    int ri = wh * 7 + i1, ci = ww * 7 + j1;
    int rid = (ri < 49 ? 0 : (ri < 53 ? 1 : 2)) * 3 + (ci < 49 ? 0 : (ci < 53 ? 1 : 2));

    const float scale = 0.17677669529663687f;  // 32^-0.5
    float s[49];
    float smax = -1e30f;
    #pragma unroll
    for (int m = 0; m < 49; ++m) {
        const fvec4* kr = (const fvec4*)Kl[hl][m];
        float a = 0.f;
        #pragma unroll
        for (int t = 0; t < 8; ++t) {
            fvec4 kv = kr[t];
            a += q[t * 4 + 0] * kv[0];
            a += q[t * 4 + 1] * kv[1];
            a += q[t * 4 + 2] * kv[2];
            a += q[t * 4 + 3] * kv[3];
        }
        int i2 = m / 7, j2 = m % 7;                     // folds to constants (unrolled)
        float sv = a * scale + bl[((i1 - i2 + 6) * 13 + (j1 - j2 + 6)) * 6 + h];
        int r2 = wh * 7 + i2, c2 = ww * 7 + j2;
        int rid2 = (r2 < 49 ? 0 : (r2 < 53 ? 1 : 2)) * 3 + (c2 < 49 ? 0 : (c2 < 53 ? 1 : 2));
        if (rid2 != rid) sv -= 100.f;                   // shift-window mask
        s[m] = sv;
        smax = fmaxf(smax, sv);
    }
    float ssum = 0.f;
    #pragma unroll
    for (int m = 0; m < 49; ++m) {
        float e = __expf(s[m] - smax);
        s[m] = e;
        ssum += e;
    }
    float inv = 1.f / ssum;
    float o[32];
    #pragma unroll
    for (int d = 0; d < 32; ++d) o[d] = 0.f;
    #pragma unroll
    for (int m = 0; m < 49; ++m) {
        float p = s[m] * inv;
        const fvec4* vr = (const fvec4*)Vl[hl][m];
        #pragma unroll
        for (int t = 0; t < 8; ++t) {
            fvec4 vv = vr[t];
            o[t * 4 + 0] += p * vv[0];
            o[t * 4 + 1] += p * vv[1];
            o[t * 4 + 2] += p * vv[2];
            o[t * 4 + 3] += p * vv[3];
        }
    }
    unsigned short* dst = awin + ((size_t)w * 49 + r) * 192 + h * 32;
    #pragma unroll
    for (int d = 0; d < 32; ++d) dst[d] = f2bf(o[d]);
}

extern "C" void kernel_launch(void* const* d_in, const int* in_sizes, int n_in,
                              void* d_out, int out_size, void* d_ws, size_t ws_size,
                              hipStream_t stream) {
    const float* x      = (const float*)d_in[0];
    const float* n1g    = (const float*)d_in[1];
    const float* n1b    = (const float*)d_in[2];
    const float* qkv_w  = (const float*)d_in[3];
    const float* qkv_b  = (const float*)d_in[4];
    const float* btab   = (const float*)d_in[5];
    const float* proj_w = (const float*)d_in[6];
    const float* proj_b = (const float*)d_in[7];
    const float* n2g    = (const float*)d_in[8];
    const float* n2b    = (const float*)d_in[9];
    const float* fc1_w  = (const float*)d_in[10];
    const float* fc1_b  = (const float*)d_in[11];
    const float* fc2_w  = (const float*)d_in[12];
    const float* fc2_b  = (const float*)d_in[13];
    float* out = (float*)d_out;

    // workspace layout (all 256B aligned; total = 540,377,088 B)
    char* p = (char*)d_ws;
    size_t off = 0;
    auto alloc = [&](size_t bytes) {
        char* r = p + off;
        off = (off + bytes + 255) & ~(size_t)255;
        return r;
    };
    unsigned short* wq   = (unsigned short*)alloc((size_t)576 * 192 * 2);
    unsigned short* wp   = (unsigned short*)alloc((size_t)192 * 192 * 2);
    unsigned short* w1   = (unsigned short*)alloc((size_t)768 * 192 * 2);
    unsigned short* w2   = (unsigned short*)alloc((size_t)192 * 768 * 2);
    unsigned short* hwin = (unsigned short*)alloc((size_t)200704 * 192 * 2);  // reused: awin
    unsigned short* qkvb = (unsigned short*)alloc((size_t)200704 * 576 * 2);  // reused: h2
    float*          xres = (float*)alloc((size_t)200704 * 192 * 4);
    unsigned short* g1   = (unsigned short*)alloc((size_t)50176 * 768 * 2);
    if (ws_size < off) return;  // workspace too small: bail (output stays poisoned)

    cvt_kernel<<<432, 256, 0, stream>>>(qkv_w, wq, 110592);
    cvt_kernel<<<144, 256, 0, stream>>>(proj_w, wp, 36864);
    cvt_kernel<<<576, 256, 0, stream>>>(fc1_w, w1, 147456);
    cvt_kernel<<<576, 256, 0, stream>>>(fc2_w, w2, 147456);

    // LN1 + shift + window partition
    ln_kernel<<<50176, 256, 0, stream>>>(x, n1g, n1b, hwin, 0);
    // QKV: (200704x192) @ (576x192)^T
    gemm_nt<0><<<dim3(9, 1568), 256, 0, stream>>>(hwin, wq, qkv_b, 192, 576, 0, qkvb, nullptr, nullptr);
    // attention: 4096 windows x 6 heads, 2 blocks/window
    attn_kernel<<<8192, 192, 0, stream>>>(qkvb, btab, hwin /* awin reuse */);
    // proj + window reverse + residual -> xres
    gemm_nt<2><<<dim3(3, 1568), 256, 0, stream>>>(hwin, wp, proj_b, 192, 192, 0, nullptr, xres, x);
    // LN2
    unsigned short* h2 = qkvb;
    ln_kernel<<<50176, 256, 0, stream>>>(xres, n2g, n2b, h2, 1);
    // MLP, chunked over M to bound the GELU intermediate
    for (int c = 0; c < 4; ++c) {
        int mb = c * 50176;
        gemm_nt<1><<<dim3(12, 392), 256, 0, stream>>>(h2 + (size_t)mb * 192, w1, fc1_b, 192, 768, 0,
                                                      g1, nullptr, nullptr);
        gemm_nt<3><<<dim3(3, 392), 256, 0, stream>>>(g1, w2, fc2_b, 768, 192, mb,
                                                     nullptr, out, xres);
    }
}

// Round 2
// 1132.726 us; speedup vs baseline: 1.1467x; 1.1467x over previous
//
#include <hip/hip_runtime.h>
#include <math.h>

typedef __attribute__((ext_vector_type(8))) short short8;
typedef __attribute__((ext_vector_type(4))) float floatx4;
typedef __attribute__((ext_vector_type(4))) float fvec4;

__device__ __forceinline__ float bf2f(unsigned short u) {
    union { unsigned int i; float f; } v;
    v.i = ((unsigned int)u) << 16;
    return v.f;
}
__device__ __forceinline__ unsigned short f2bf(float f) {
    union { float f; unsigned int i; } v;
    v.f = f;
    return (unsigned short)((v.i + 0x7FFFu + ((v.i >> 16) & 1u)) >> 16);
}
// async global->LDS, 16B per lane; LDS dest must be wave-uniform base (lane i -> base + 16*i)
__device__ __forceinline__ void async16(const void* g, void* l) {
    __builtin_amdgcn_global_load_lds((const __attribute__((address_space(1))) void*)g,
                                     (__attribute__((address_space(3))) void*)l, 16, 0, 0);
}
__device__ __forceinline__ int region(int c) { return c < 49 ? 0 : (c < 53 ? 1 : 2); }

// ---------------- fp32 -> bf16 convert ----------------
__global__ __launch_bounds__(256) void cvt_kernel(const float* __restrict__ s,
                                                  unsigned short* __restrict__ d, int n) {
    int i = blockIdx.x * 256 + threadIdx.x;
    if (i < n) d[i] = f2bf(s[i]);
}

// ---------------- LayerNorm over C=192, one wave per row ----------------
__global__ __launch_bounds__(256) void ln_kernel(const float* __restrict__ src,
                                                 const float* __restrict__ gw,
                                                 const float* __restrict__ bw,
                                                 unsigned short* __restrict__ dst,
                                                 int mode) {
    int o = blockIdx.x * 4 + (threadIdx.x >> 6);
    int lane = threadIdx.x & 63;
    size_t srow;
    if (mode == 0) {
        int win = o / 49, n = o % 49;
        int b = win >> 6, wl = win & 63;
        int wh = wl >> 3, ww = wl & 7;
        int i = n / 7, j = n % 7;
        int pr = (wh * 7 + i + 3) % 56;   // roll(-3)
        int pc = (ww * 7 + j + 3) % 56;
        srow = ((size_t)b * 3136 + (size_t)(pr * 56 + pc)) * 192;
    } else {
        srow = (size_t)o * 192;
    }
    float v0 = src[srow + lane];
    float v1 = src[srow + lane + 64];
    float v2 = src[srow + lane + 128];
    float s = v0 + v1 + v2;
    float s2 = v0 * v0 + v1 * v1 + v2 * v2;
    #pragma unroll
    for (int off = 32; off > 0; off >>= 1) {
        s += __shfl_xor(s, off);
        s2 += __shfl_xor(s2, off);
    }
    float mean = s * (1.0f / 192.0f);
    float var = s2 * (1.0f / 192.0f) - mean * mean;
    float inv = rsqrtf(var + 1e-5f);
    size_t drow = (size_t)o * 192;
    dst[drow + lane]       = f2bf((v0 - mean) * inv * gw[lane]       + bw[lane]);
    dst[drow + lane + 64]  = f2bf((v1 - mean) * inv * gw[lane + 64]  + bw[lane + 64]);
    dst[drow + lane + 128] = f2bf((v2 - mean) * inv * gw[lane + 128] + bw[lane + 128]);
}

// ---------------- GEMM: C[m][n] = sum_k A[m][k]*W[n][k] (+bias, epilogue) ----------
// Tile 128x64, BK=32, 4 waves (2x2). Staging via global_load_lds (16B/lane), LDS UNPADDED
// (lane->LDS contiguity contract). EPI: 0 qkv, 1 fc1(gelu), 2 proj(+reverse+resid), 3 fc2(+resid).
template <int EPI>
__global__ __launch_bounds__(256) void gemm_nt(const unsigned short* __restrict__ A,
                                               const unsigned short* __restrict__ W,
                                               const float* __restrict__ bias,
                                               int K, int ldo, int mbase,
                                               unsigned short* __restrict__ outb,
                                               float* __restrict__ outf,
                                               const float* __restrict__ resid) {
    __shared__ __align__(16) unsigned short Al[128][32];
    __shared__ __align__(16) unsigned short Wl[64][32];
    int tid = threadIdx.x;
    int lane = tid & 63;
    int wv = tid >> 6;
    int wm = wv >> 1, wn = wv & 1;
    int m0 = blockIdx.y * 128;
    int n0 = blockIdx.x * 64;
    int quad = lane >> 4, l15 = lane & 15;

    // staging: wave wv covers A rows [wv*32, wv*32+32) in 2 issues, W rows [wv*16, wv*16+16) in 1
    int srow = lane >> 2;               // 0..15
    int scol = (lane & 3) * 8;          // element offset
    const unsigned short* aP0 = A + (size_t)(m0 + wv * 32 + srow) * K + scol;
    const unsigned short* aP1 = aP0 + (size_t)16 * K;
    const unsigned short* wP  = W + (size_t)(n0 + wv * 16 + srow) * K + scol;
    unsigned short* lA0 = &Al[wv * 32][0];
    unsigned short* lA1 = &Al[wv * 32 + 16][0];
    unsigned short* lW  = &Wl[wv * 16][0];

    floatx4 acc[4][2];
    floatx4 zero = {0.f, 0.f, 0.f, 0.f};
    #pragma unroll
    for (int a = 0; a < 4; ++a)
        #pragma unroll
        for (int b = 0; b < 2; ++b) acc[a][b] = zero;

    for (int kt = 0; kt < K; kt += 32) {
        __syncthreads();                 // prev iter's LDS reads done
        async16(aP0 + kt, lA0);
        async16(aP1 + kt, lA1);
        async16(wP + kt, lW);
        __syncthreads();                 // drains vmcnt -> LDS valid
        short8 af[4], wf[2];
        #pragma unroll
        for (int mt = 0; mt < 4; ++mt)
            af[mt] = *(const short8*)&Al[wm * 64 + mt * 16 + l15][quad * 8];
        #pragma unroll
        for (int nt = 0; nt < 2; ++nt)
            wf[nt] = *(const short8*)&Wl[wn * 32 + nt * 16 + l15][quad * 8];
        #pragma unroll
        for (int mt = 0; mt < 4; ++mt)
            #pragma unroll
            for (int nt = 0; nt < 2; ++nt)
                acc[mt][nt] = __builtin_amdgcn_mfma_f32_16x16x32_bf16(af[mt], wf[nt], acc[mt][nt], 0, 0, 0);
    }

    #pragma unroll
    for (int mt = 0; mt < 4; ++mt) {
        #pragma unroll
        for (int nt = 0; nt < 2; ++nt) {
            #pragma unroll
            for (int r = 0; r < 4; ++r) {
                int m = m0 + wm * 64 + mt * 16 + quad * 4 + r;
                int n = n0 + wn * 32 + nt * 16 + l15;
                float v = acc[mt][nt][r] + bias[n];
                if (EPI == 0) {
                    outb[(size_t)m * ldo + n] = f2bf(v);
                } else if (EPI == 1) {
                    float g = 0.5f * v * (1.0f + erff(v * 0.70710678118654752f));
                    outb[(size_t)m * ldo + n] = f2bf(g);
                } else if (EPI == 2) {
                    int win = m / 49, np = m % 49;
                    int b = win >> 6, wl = win & 63;
                    int wh = wl >> 3, ww = wl & 7;
                    int i = np / 7, j = np % 7;
                    int pr = (wh * 7 + i + 3) % 56;  // window-reverse + roll(+3)
                    int pc = (ww * 7 + j + 3) % 56;
                    size_t dst = ((size_t)b * 3136 + (size_t)(pr * 56 + pc)) * 192 + n;
                    outf[dst] = resid[dst] + v;
                } else {
                    size_t dst = (size_t)(mbase + m) * ldo + n;
                    outf[dst] = resid[dst] + v;
                }
            }
        }
    }
}

// ---------------- MFMA windowed attention ----------------
// block = 192 threads = 3 waves, one (window, head) per wave; grid 8192 (2 blocks/window).
// Per wave: S = Q@K^T (16 mfma, frags straight from global), softmax in C-layout,
// P -> LDS bf16 (stride 72), O = P@V (16 mfma, V^T staged in LDS). N=49 padded to 64.
__global__ __launch_bounds__(192) void attn_kernel(const unsigned short* __restrict__ qkv,
                                                   const float* __restrict__ btab,
                                                   unsigned short* __restrict__ awin) {
    __shared__ __align__(16) unsigned short VT[3][32][72];  // V^T per head: [d][key]
    __shared__ __align__(16) unsigned short Pb[3][64][72];  // P per head: [query][key]
    __shared__ float bl[1014];
    int w = blockIdx.x >> 1;
    int hb = (blockIdx.x & 1) * 3;
    int tid = threadIdx.x;
    int hl = tid >> 6;
    int lane = tid & 63;
    int h = hb + hl;
    int quad = lane >> 4, l15 = lane & 15;
    const unsigned short* base = qkv + (size_t)w * 49 * 576;

    for (int i = tid; i < 1014; i += 192) bl[i] = btab[i];
    // zero VT pad keys 48..63 (NaN x 0 hazard), then stage V^T (same-wave order: zeros first)
    for (int idx = lane; idx < 512; idx += 64) {
        VT[hl][idx >> 4][48 + (idx & 15)] = 0;
    }
    for (int idx = lane; idx < 196; idx += 64) {
        int r = idx >> 2, c8 = (idx & 3) * 8;
        short8 vv = *(const short8*)(base + (size_t)r * 576 + 384 + h * 32 + c8);
        #pragma unroll
        for (int e = 0; e < 8; ++e) VT[hl][c8 + e][r] = (unsigned short)vv[e];
    }
    // Q A-frags / K B-frags directly from global (16B aligned). Rows >=49 read finite garbage.
    short8 qf[4], kf[4];
    #pragma unroll
    for (int mt = 0; mt < 4; ++mt)
        qf[mt] = *(const short8*)(base + (size_t)(mt * 16 + l15) * 576 + h * 32 + quad * 8);
    #pragma unroll
    for (int nt = 0; nt < 4; ++nt)
        kf[nt] = *(const short8*)(base + (size_t)(nt * 16 + l15) * 576 + 192 + h * 32 + quad * 8);

    floatx4 zero = {0.f, 0.f, 0.f, 0.f};
    floatx4 S[4][4];
    #pragma unroll
    for (int mt = 0; mt < 4; ++mt)
        #pragma unroll
        for (int nt = 0; nt < 4; ++nt)
            S[mt][nt] = __builtin_amdgcn_mfma_f32_16x16x32_bf16(qf[mt], kf[nt], zero, 0, 0, 0);

    __syncthreads();  // bl staged (VT/Pb are same-wave-private)

    int wl = w & 63, wh7 = (wl >> 3) * 7, ww7 = (wl & 7) * 7;
    // column-side (key) precompute: col = nt*16 + l15
    int coli[4], colj[4], colrid[4], colok[4];
    #pragma unroll
    for (int nt = 0; nt < 4; ++nt) {
        int c = nt * 16 + l15;
        colok[nt] = c < 49;
        int ci = c / 7;
        coli[nt] = ci;
        colj[nt] = c - ci * 7;
        colrid[nt] = region(wh7 + ci) * 3 + region(ww7 + (c - ci * 7));
    }
    const float scale = 0.17677669529663687f;  // 32^-0.5
    float rinv[4][4];
    #pragma unroll
    for (int mt = 0; mt < 4; ++mt) {
        #pragma unroll
        for (int rr = 0; rr < 4; ++rr) {
            int r = mt * 16 + quad * 4 + rr;   // query row (garbage rows >=49 never stored)
            int ri = r / 7, rj = r - ri * 7;
            int rowrid = region(wh7 + ri) * 3 + region(ww7 + rj);
            float vv[4];
            float mx = -3.0e38f;
            #pragma unroll
            for (int nt = 0; nt < 4; ++nt) {
                float v;
                if (colok[nt]) {
                    v = S[mt][nt][rr] * scale +
                        bl[((ri - coli[nt] + 6) * 13 + (rj - colj[nt] + 6)) * 6 + h];
                    if (colrid[nt] != rowrid) v -= 100.f;
                } else {
                    v = -3.0e38f;
                }
                vv[nt] = v;
                mx = fmaxf(mx, v);
            }
            #pragma unroll
            for (int s = 1; s <= 8; s <<= 1) mx = fmaxf(mx, __shfl_xor(mx, s));
            float sum = 0.f;
            #pragma unroll
            for (int nt = 0; nt < 4; ++nt) {
                float e = __expf(vv[nt] - mx);
                vv[nt] = e;
                sum += e;
            }
            #pragma unroll
            for (int s = 1; s <= 8; s <<= 1) sum += __shfl_xor(sum, s);
            rinv[mt][rr] = 1.f / sum;
            #pragma unroll
            for (int nt = 0; nt < 4; ++nt) Pb[hl][r][nt * 16 + l15] = f2bf(vv[nt]);
        }
    }

    // O = P @ V  (A = Pb rows, B = VT rows = head-dims; K=64 in 2 steps)
    floatx4 O[4][2];
    #pragma unroll
    for (int mt = 0; mt < 4; ++mt)
        #pragma unroll
        for (int nt = 0; nt < 2; ++nt) O[mt][nt] = zero;
    #pragma unroll
    for (int ks = 0; ks < 2; ++ks) {
        short8 vf[2];
        #pragma unroll
        for (int nt = 0; nt < 2; ++nt)
            vf[nt] = *(const short8*)&VT[hl][nt * 16 + l15][ks * 32 + quad * 8];
        #pragma unroll
        for (int mt = 0; mt < 4; ++mt) {
            short8 pf = *(const short8*)&Pb[hl][mt * 16 + l15][ks * 32 + quad * 8];
            #pragma unroll
            for (int nt = 0; nt < 2; ++nt)
                O[mt][nt] = __builtin_amdgcn_mfma_f32_16x16x32_bf16(pf, vf[nt], O[mt][nt], 0, 0, 0);
        }
    }
    #pragma unroll
    for (int mt = 0; mt < 4; ++mt) {
        #pragma unroll
        for (int rr = 0; rr < 4; ++rr) {
            int r = mt * 16 + quad * 4 + rr;
            if (r < 49) {
                float inv = rinv[mt][rr];
                #pragma unroll
                for (int nt = 0; nt < 2; ++nt)
                    awin[((size_t)w * 49 + r) * 192 + h * 32 + nt * 16 + l15] =
                        f2bf(O[mt][nt][rr] * inv);
            }
        }
    }
}

extern "C" void kernel_launch(void* const* d_in, const int* in_sizes, int n_in,
                              void* d_out, int out_size, void* d_ws, size_t ws_size,
                              hipStream_t stream) {
    const float* x      = (const float*)d_in[0];
    const float* n1g    = (const float*)d_in[1];
    const float* n1b    = (const float*)d_in[2];
    const float* qkv_w  = (const float*)d_in[3];
    const float* qkv_b  = (const float*)d_in[4];
    const float* btab   = (const float*)d_in[5];
    const float* proj_w = (const float*)d_in[6];
    const float* proj_b = (const float*)d_in[7];
    const float* n2g    = (const float*)d_in[8];
    const float* n2b    = (const float*)d_in[9];
    const float* fc1_w  = (const float*)d_in[10];
    const float* fc1_b  = (const float*)d_in[11];
    const float* fc2_w  = (const float*)d_in[12];
    const float* fc2_b  = (const float*)d_in[13];
    float* out = (float*)d_out;

    char* p = (char*)d_ws;
    size_t off = 0;
    auto alloc = [&](size_t bytes) {
        char* r = p + off;
        off = (off + bytes + 255) & ~(size_t)255;
        return r;
    };
    unsigned short* wq   = (unsigned short*)alloc((size_t)576 * 192 * 2);
    unsigned short* wp   = (unsigned short*)alloc((size_t)192 * 192 * 2);
    unsigned short* w1   = (unsigned short*)alloc((size_t)768 * 192 * 2);
    unsigned short* w2   = (unsigned short*)alloc((size_t)192 * 768 * 2);
    unsigned short* hwin = (unsigned short*)alloc((size_t)200704 * 192 * 2);  // reused: awin
    unsigned short* qkvb = (unsigned short*)alloc((size_t)200704 * 576 * 2);  // reused: h2
    float*          xres = (float*)alloc((size_t)200704 * 192 * 4);
    unsigned short* g1   = (unsigned short*)alloc((size_t)50176 * 768 * 2);
    if (ws_size < off) return;

    cvt_kernel<<<432, 256, 0, stream>>>(qkv_w, wq, 110592);
    cvt_kernel<<<144, 256, 0, stream>>>(proj_w, wp, 36864);
    cvt_kernel<<<576, 256, 0, stream>>>(fc1_w, w1, 147456);
    cvt_kernel<<<576, 256, 0, stream>>>(fc2_w, w2, 147456);

    ln_kernel<<<50176, 256, 0, stream>>>(x, n1g, n1b, hwin, 0);
    gemm_nt<0><<<dim3(9, 1568), 256, 0, stream>>>(hwin, wq, qkv_b, 192, 576, 0, qkvb, nullptr, nullptr);
    attn_kernel<<<8192, 192, 0, stream>>>(qkvb, btab, hwin /* awin reuse */);
    gemm_nt<2><<<dim3(3, 1568), 256, 0, stream>>>(hwin, wp, proj_b, 192, 192, 0, nullptr, xres, x);
    unsigned short* h2 = qkvb;
    ln_kernel<<<50176, 256, 0, stream>>>(xres, n2g, n2b, h2, 1);
    for (int c = 0; c < 4; ++c) {
        int mb = c * 50176;
        gemm_nt<1><<<dim3(12, 392), 256, 0, stream>>>(h2 + (size_t)mb * 192, w1, fc1_b, 192, 768, 0,
                                                      g1, nullptr, nullptr);
        gemm_nt<3><<<dim3(3, 392), 256, 0, stream>>>(g1, w2, fc2_b, 768, 192, mb,
                                                     nullptr, out, xres);
    }
}

// Round 3
// 1101.395 us; speedup vs baseline: 1.1793x; 1.0284x over previous
//
#include <hip/hip_runtime.h>
#include <hip/hip_bf16.h>
#include <math.h>

typedef __attribute__((ext_vector_type(8))) short short8;
typedef __attribute__((ext_vector_type(4))) float floatx4;

__device__ __forceinline__ float bf2f(unsigned short u) {
    union { unsigned int i; float f; } v;
    v.i = ((unsigned int)u) << 16;
    return v.f;
}
__device__ __forceinline__ unsigned short f2bf(float f) {
    union { float f; unsigned int i; } v;
    v.f = f;
    return (unsigned short)((v.i + 0x7FFFu + ((v.i >> 16) & 1u)) >> 16);
}
__device__ __forceinline__ void async16(const void* g, void* l) {
    __builtin_amdgcn_global_load_lds((const __attribute__((address_space(1))) void*)g,
                                     (__attribute__((address_space(3))) void*)l, 16, 0, 0);
}

// ---------------- fp32 -> bf16 convert (optional head-scale on first `cut` elems) ----
__global__ __launch_bounds__(256) void cvt_kernel(const float* __restrict__ s,
                                                  unsigned short* __restrict__ d, int n,
                                                  int cut, float scale) {
    int i = blockIdx.x * 256 + threadIdx.x;
    if (i < n) d[i] = f2bf(s[i] * (i < cut ? scale : 1.0f));
}
__global__ __launch_bounds__(256) void biasscale_kernel(const float* __restrict__ s,
                                                        float* __restrict__ d, int n,
                                                        int cut, float scale) {
    int i = blockIdx.x * 256 + threadIdx.x;
    if (i < n) d[i] = s[i] * (i < cut ? scale : 1.0f);
}

// ---------------- bias+mask accumulator-init table ----------------
// tbl[cls][h][query 64][key 64] fp32. key>=49 -> -3e38 (pad), query>=49 -> 0 (unused).
// cls = (wh==7)*2 + (ww==7): mask regions only differ at the bottom/right window row/col.
__global__ __launch_bounds__(256) void bmt_kernel(const float* __restrict__ btab,
                                                  float* __restrict__ tbl) {
    int idx = blockIdx.x * 256 + threadIdx.x;  // < 4*6*64*64
    int key = idx & 63;
    int q = (idx >> 6) & 63;
    int h = (idx >> 12) % 6;
    int cls = idx / (4096 * 6);
    float v;
    if (key >= 49) v = -3.0e38f;
    else if (q >= 49) v = 0.0f;
    else {
        int qi = q / 7, qj = q % 7, ki = key / 7, kj = key % 7;
        v = btab[((qi - ki + 6) * 13 + (qj - kj + 6)) * 6 + h];
        int whT = (cls >> 1) & 1, wwT = cls & 1;
        int rq = (whT ? (qi < 4 ? 1 : 2) : 0) * 3 + (wwT ? (qj < 4 ? 1 : 2) : 0);
        int rk = (whT ? (ki < 4 ? 1 : 2) : 0) * 3 + (wwT ? (kj < 4 ? 1 : 2) : 0);
        if (rq != rk) v -= 100.0f;
    }
    tbl[idx] = v;
}

// ---------------- LayerNorm over C=192, one wave per row ----------------
__global__ __launch_bounds__(256) void ln_kernel(const float* __restrict__ src,
                                                 const float* __restrict__ gw,
                                                 const float* __restrict__ bw,
                                                 unsigned short* __restrict__ dst,
                                                 int mode) {
    int o = blockIdx.x * 4 + (threadIdx.x >> 6);
    int lane = threadIdx.x & 63;
    size_t srow;
    if (mode == 0) {
        int win = o / 49, n = o % 49;
        int b = win >> 6, wl = win & 63;
        int wh = wl >> 3, ww = wl & 7;
        int i = n / 7, j = n % 7;
        int pr = (wh * 7 + i + 3) % 56;   // roll(-3)
        int pc = (ww * 7 + j + 3) % 56;
        srow = ((size_t)b * 3136 + (size_t)(pr * 56 + pc)) * 192;
    } else {
        srow = (size_t)o * 192;
    }
    float v0 = src[srow + lane];
    float v1 = src[srow + lane + 64];
    float v2 = src[srow + lane + 128];
    float s = v0 + v1 + v2;
    float s2 = v0 * v0 + v1 * v1 + v2 * v2;
    #pragma unroll
    for (int off = 32; off > 0; off >>= 1) {
        s += __shfl_xor(s, off);
        s2 += __shfl_xor(s2, off);
    }
    float mean = s * (1.0f / 192.0f);
    float var = s2 * (1.0f / 192.0f) - mean * mean;
    float inv = rsqrtf(var + 1e-5f);
    size_t drow = (size_t)o * 192;
    dst[drow + lane]       = f2bf((v0 - mean) * inv * gw[lane]       + bw[lane]);
    dst[drow + lane + 64]  = f2bf((v1 - mean) * inv * gw[lane + 64]  + bw[lane + 64]);
    dst[drow + lane + 128] = f2bf((v2 - mean) * inv * gw[lane + 128] + bw[lane + 128]);
}

// ---------------- GEMM: C[m][n] = sum_k A[m][k]*W[n][k] (+bias, epilogue) ----------
template <int EPI>
__global__ __launch_bounds__(256) void gemm_nt(const unsigned short* __restrict__ A,
                                               const unsigned short* __restrict__ W,
                                               const float* __restrict__ bias,
                                               int K, int ldo, int mbase,
                                               unsigned short* __restrict__ outb,
                                               float* __restrict__ outf,
                                               const float* __restrict__ resid) {
    __shared__ __align__(16) unsigned short Al[128][32];
    __shared__ __align__(16) unsigned short Wl[64][32];
    int tid = threadIdx.x;
    int lane = tid & 63;
    int wv = tid >> 6;
    int wm = wv >> 1, wn = wv & 1;
    int m0 = blockIdx.y * 128;
    int n0 = blockIdx.x * 64;
    int quad = lane >> 4, l15 = lane & 15;

    int srow = lane >> 2;
    int scol = (lane & 3) * 8;
    const unsigned short* aP0 = A + (size_t)(m0 + wv * 32 + srow) * K + scol;
    const unsigned short* aP1 = aP0 + (size_t)16 * K;
    const unsigned short* wP  = W + (size_t)(n0 + wv * 16 + srow) * K + scol;
    unsigned short* lA0 = &Al[wv * 32][0];
    unsigned short* lA1 = &Al[wv * 32 + 16][0];
    unsigned short* lW  = &Wl[wv * 16][0];

    floatx4 acc[4][2];
    floatx4 zero = {0.f, 0.f, 0.f, 0.f};
    #pragma unroll
    for (int a = 0; a < 4; ++a)
        #pragma unroll
        for (int b = 0; b < 2; ++b) acc[a][b] = zero;

    for (int kt = 0; kt < K; kt += 32) {
        __syncthreads();
        async16(aP0 + kt, lA0);
        async16(aP1 + kt, lA1);
        async16(wP + kt, lW);
        __syncthreads();
        short8 af[4], wf[2];
        #pragma unroll
        for (int mt = 0; mt < 4; ++mt)
            af[mt] = *(const short8*)&Al[wm * 64 + mt * 16 + l15][quad * 8];
        #pragma unroll
        for (int nt = 0; nt < 2; ++nt)
            wf[nt] = *(const short8*)&Wl[wn * 32 + nt * 16 + l15][quad * 8];
        #pragma unroll
        for (int mt = 0; mt < 4; ++mt)
            #pragma unroll
            for (int nt = 0; nt < 2; ++nt)
                acc[mt][nt] = __builtin_amdgcn_mfma_f32_16x16x32_bf16(af[mt], wf[nt], acc[mt][nt], 0, 0, 0);
    }

    #pragma unroll
    for (int mt = 0; mt < 4; ++mt) {
        #pragma unroll
        for (int nt = 0; nt < 2; ++nt) {
            #pragma unroll
            for (int r = 0; r < 4; ++r) {
                int m = m0 + wm * 64 + mt * 16 + quad * 4 + r;
                int n = n0 + wn * 32 + nt * 16 + l15;
                float v = acc[mt][nt][r] + bias[n];
                if (EPI == 0) {
                    outb[(size_t)m * ldo + n] = f2bf(v);
                } else if (EPI == 1) {
                    float g = 0.5f * v * (1.0f + erff(v * 0.70710678118654752f));
                    outb[(size_t)m * ldo + n] = f2bf(g);
                } else if (EPI == 2) {
                    int win = m / 49, np = m % 49;
                    int b = win >> 6, wl = win & 63;
                    int wh = wl >> 3, ww = wl & 7;
                    int i = np / 7, j = np % 7;
                    int pr = (wh * 7 + i + 3) % 56;
                    int pc = (ww * 7 + j + 3) % 56;
                    size_t dst = ((size_t)b * 3136 + (size_t)(pr * 56 + pc)) * 192 + n;
                    outf[dst] = resid[dst] + v;
                } else {
                    size_t dst = (size_t)(mbase + m) * ldo + n;
                    outf[dst] = resid[dst] + v;
                }
            }
        }
    }
}

// ---------------- MFMA windowed attention, S^T formulation ----------------
// 3 waves/block, one (window, head) per wave. S^T = K·Qs^T (acc-init = bias+mask table),
// softmax over keys = in-lane + 2 shfl, P normalized+packed -> Pb (b64 writes, row-major
// [query][key]), O = Pb·V with V B-frags read straight from global. No barriers.
__global__ __launch_bounds__(192) void attn_kernel(const unsigned short* __restrict__ qkv,
                                                   const float* __restrict__ tbl,
                                                   unsigned short* __restrict__ awin) {
    __shared__ __align__(16) unsigned short Pb[3][64][72];
    int w = blockIdx.x >> 1;
    int hb = (blockIdx.x & 1) * 3;
    int hl = threadIdx.x >> 6;
    int h = hb + hl;
    int lane = threadIdx.x & 63;
    int quad = lane >> 4, l15 = lane & 15;
    const unsigned short* base = qkv + (size_t)w * 49 * 576;
    int wl = w & 63;
    int cls = ((wl >> 3) == 7 ? 2 : 0) + ((wl & 7) == 7 ? 1 : 0);
    const float* tb = tbl + (size_t)(cls * 6 + h) * 4096;

    // A = K rows, B = Q rows (q pre-scaled into qkv_w/qkv_b)
    short8 kf[4], qf[4];
    #pragma unroll
    for (int mt = 0; mt < 4; ++mt)
        kf[mt] = *(const short8*)(base + (size_t)(mt * 16 + l15) * 576 + 192 + h * 32 + quad * 8);
    #pragma unroll
    for (int nt = 0; nt < 4; ++nt)
        qf[nt] = *(const short8*)(base + (size_t)(nt * 16 + l15) * 576 + h * 32 + quad * 8);

    floatx4 S[4][4];
    #pragma unroll
    for (int mt = 0; mt < 4; ++mt)
        #pragma unroll
        for (int nt = 0; nt < 4; ++nt) {
            floatx4 cinit = *(const floatx4*)(tb + (nt * 16 + l15) * 64 + mt * 16 + quad * 4);
            S[mt][nt] = __builtin_amdgcn_mfma_f32_16x16x32_bf16(kf[mt], qf[nt], cinit, 0, 0, 0);
        }

    // exp (no max-sub: scores bounded ~±1; masked=-100 -> 0; key-pad=-3e38 -> 0)
    #pragma unroll
    for (int mt = 0; mt < 4; ++mt)
        #pragma unroll
        for (int nt = 0; nt < 4; ++nt)
            #pragma unroll
            for (int rr = 0; rr < 4; ++rr)
                S[mt][nt][rr] = __expf(S[mt][nt][rr]);

    // per-query sums: in-lane over (mt,rr), then reduce 4 quads
    float rinv[4];
    #pragma unroll
    for (int nt = 0; nt < 4; ++nt) {
        float s = 0.f;
        #pragma unroll
        for (int mt = 0; mt < 4; ++mt)
            s += (S[mt][nt][0] + S[mt][nt][1]) + (S[mt][nt][2] + S[mt][nt][3]);
        s += __shfl_xor(s, 16);
        s += __shfl_xor(s, 32);
        rinv[nt] = 1.0f / s;
    }

    // normalize + pack 4 consecutive keys -> b64 write, Pb row-major [query][key]
    #pragma unroll
    for (int mt = 0; mt < 4; ++mt) {
        #pragma unroll
        for (int nt = 0; nt < 4; ++nt) {
            __hip_bfloat162 p0 = __float22bfloat162_rn(
                make_float2(S[mt][nt][0] * rinv[nt], S[mt][nt][1] * rinv[nt]));
            __hip_bfloat162 p1 = __float22bfloat162_rn(
                make_float2(S[mt][nt][2] * rinv[nt], S[mt][nt][3] * rinv[nt]));
            union { __hip_bfloat162 h2[2]; uint2 u; } pk;
            pk.h2[0] = p0;
            pk.h2[1] = p1;
            *(uint2*)&Pb[hl][nt * 16 + l15][mt * 16 + quad * 4] = pk.u;
        }
    }

    // O = Pb · V ; V B-frags from global: lane l15 -> d, reg j -> key (imm offsets j*1152B)
    floatx4 O[4][2];
    floatx4 zero = {0.f, 0.f, 0.f, 0.f};
    #pragma unroll
    for (int mt = 0; mt < 4; ++mt)
        #pragma unroll
        for (int nt = 0; nt < 2; ++nt) O[mt][nt] = zero;
    #pragma unroll
    for (int ks = 0; ks < 2; ++ks) {
        short8 vf[2];
        #pragma unroll
        for (int nt = 0; nt < 2; ++nt) {
            const unsigned short* vb =
                base + (size_t)(ks * 32 + quad * 8) * 576 + 384 + h * 32 + nt * 16 + l15;
            #pragma unroll
            for (int j = 0; j < 8; ++j) vf[nt][j] = (short)vb[(size_t)j * 576];
        }
        #pragma unroll
        for (int mt = 0; mt < 4; ++mt) {
            short8 pf = *(const short8*)&Pb[hl][mt * 16 + l15][ks * 32 + quad * 8];
            #pragma unroll
            for (int nt = 0; nt < 2; ++nt)
                O[mt][nt] = __builtin_amdgcn_mfma_f32_16x16x32_bf16(pf, vf[nt], O[mt][nt], 0, 0, 0);
        }
    }
    #pragma unroll
    for (int mt = 0; mt < 4; ++mt) {
        #pragma unroll
        for (int rr = 0; rr < 4; ++rr) {
            int q = mt * 16 + quad * 4 + rr;
            if (q < 49) {
                #pragma unroll
                for (int nt = 0; nt < 2; ++nt)
                    awin[((size_t)w * 49 + q) * 192 + h * 32 + nt * 16 + l15] =
                        f2bf(O[mt][nt][rr]);
            }
        }
    }
}

extern "C" void kernel_launch(void* const* d_in, const int* in_sizes, int n_in,
                              void* d_out, int out_size, void* d_ws, size_t ws_size,
                              hipStream_t stream) {
    const float* x      = (const float*)d_in[0];
    const float* n1g    = (const float*)d_in[1];
    const float* n1b    = (const float*)d_in[2];
    const float* qkv_w  = (const float*)d_in[3];
    const float* qkv_b  = (const float*)d_in[4];
    const float* btab   = (const float*)d_in[5];
    const float* proj_w = (const float*)d_in[6];
    const float* proj_b = (const float*)d_in[7];
    const float* n2g    = (const float*)d_in[8];
    const float* n2b    = (const float*)d_in[9];
    const float* fc1_w  = (const float*)d_in[10];
    const float* fc1_b  = (const float*)d_in[11];
    const float* fc2_w  = (const float*)d_in[12];
    const float* fc2_b  = (const float*)d_in[13];
    float* out = (float*)d_out;

    char* p = (char*)d_ws;
    size_t off = 0;
    auto alloc = [&](size_t bytes) {
        char* r = p + off;
        off = (off + bytes + 255) & ~(size_t)255;
        return r;
    };
    unsigned short* wq   = (unsigned short*)alloc((size_t)576 * 192 * 2);
    unsigned short* wp   = (unsigned short*)alloc((size_t)192 * 192 * 2);
    unsigned short* w1   = (unsigned short*)alloc((size_t)768 * 192 * 2);
    unsigned short* w2   = (unsigned short*)alloc((size_t)192 * 768 * 2);
    unsigned short* hwin = (unsigned short*)alloc((size_t)200704 * 192 * 2);  // reused: awin
    unsigned short* qkvb = (unsigned short*)alloc((size_t)200704 * 576 * 2);  // reused: h2
    float*          xres = (float*)alloc((size_t)200704 * 192 * 4);
    unsigned short* g1   = (unsigned short*)alloc((size_t)50176 * 768 * 2);
    if (ws_size < off) return;
    // tbl + scaled qkv bias live in g1's region (g1 only used later, stream-ordered)
    float* tbl   = (float*)g1;              // 98304 floats
    float* qkvbs = (float*)g1 + 98304;      // 576 floats

    const float scale = 0.17677669529663687f;  // 32^-0.5, folded into q
    cvt_kernel<<<432, 256, 0, stream>>>(qkv_w, wq, 110592, 36864, scale);
    cvt_kernel<<<144, 256, 0, stream>>>(proj_w, wp, 36864, 0, 1.0f);
    cvt_kernel<<<576, 256, 0, stream>>>(fc1_w, w1, 147456, 0, 1.0f);
    cvt_kernel<<<576, 256, 0, stream>>>(fc2_w, w2, 147456, 0, 1.0f);
    biasscale_kernel<<<3, 256, 0, stream>>>(qkv_b, qkvbs, 576, 192, scale);
    bmt_kernel<<<384, 256, 0, stream>>>(btab, tbl);

    ln_kernel<<<50176, 256, 0, stream>>>(x, n1g, n1b, hwin, 0);
    gemm_nt<0><<<dim3(9, 1568), 256, 0, stream>>>(hwin, wq, qkvbs, 192, 576, 0, qkvb, nullptr, nullptr);
    attn_kernel<<<8192, 192, 0, stream>>>(qkvb, tbl, hwin /* awin reuse */);
    gemm_nt<2><<<dim3(3, 1568), 256, 0, stream>>>(hwin, wp, proj_b, 192, 192, 0, nullptr, xres, x);
    unsigned short* h2 = qkvb;
    ln_kernel<<<50176, 256, 0, stream>>>(xres, n2g, n2b, h2, 1);
    for (int c = 0; c < 4; ++c) {
        int mb = c * 50176;
        gemm_nt<1><<<dim3(12, 392), 256, 0, stream>>>(h2 + (size_t)mb * 192, w1, fc1_b, 192, 768, 0,
                                                      g1, nullptr, nullptr);
        gemm_nt<3><<<dim3(3, 392), 256, 0, stream>>>(g1, w2, fc2_b, 768, 192, mb,
                                                     nullptr, out, xres);
    }
}